// Round 16
// baseline (1519.678 us; speedup 1.0000x reference)
//
#include <hip/hip_runtime.h>
#include <hip/hip_bf16.h>

#define HIDDEN 3072
#define INTER  8192
#define NTOK   8192   // B*S = 4*2048

typedef __attribute__((ext_vector_type(8))) short bf16x8;
typedef __attribute__((ext_vector_type(4))) float f32x4;

__device__ __forceinline__ void gload_lds16(const void* g, void* l) {
  __builtin_amdgcn_global_load_lds(
      (const __attribute__((address_space(1))) void*)g,
      (__attribute__((address_space(3))) void*)l, 16, 0, 0);
}

__device__ __forceinline__ unsigned short f2bf(float f) {
  unsigned int u = __builtin_bit_cast(unsigned int, f);
  u += 0x7fffu + ((u >> 16) & 1u);   // round-to-nearest-even
  return (unsigned short)(u >> 16);
}

// ---------------- conversion kernels ----------------

__global__ void cvt_f32_bf16(const float* __restrict__ in,
                             unsigned short* __restrict__ out, int n4) {
  int i = blockIdx.x * blockDim.x + threadIdx.x;
  if (i >= n4) return;
  float4 v = reinterpret_cast<const float4*>(in)[i];
  ushort4 o;
  o.x = f2bf(v.x); o.y = f2bf(v.y); o.z = f2bf(v.z); o.w = f2bf(v.w);
  reinterpret_cast<ushort4*>(out)[i] = o;
}

__global__ void cvt_i32_bf16(const int* __restrict__ in,
                             unsigned short* __restrict__ out, int n4) {
  int i = blockIdx.x * blockDim.x + threadIdx.x;
  if (i >= n4) return;
  int4 v = reinterpret_cast<const int4*>(in)[i];
  ushort4 o;
  o.x = f2bf((float)v.x); o.y = f2bf((float)v.y);
  o.z = f2bf((float)v.z); o.w = f2bf((float)v.w);
  reinterpret_cast<ushort4*>(out)[i] = o;
}

// W_gu convert with gate/up row interleave at 16-row granularity:
// W'-row rowp = 32*(c>>4) + 16*u + (c&15), u=0 gate / 1 up.
__global__ void cvt_wgu_perm(const int* __restrict__ in,
                             unsigned short* __restrict__ out) {
  int i4 = blockIdx.x * blockDim.x + threadIdx.x;
  const int RW = HIDDEN / 4;   // 768 int4-groups per row
  if (i4 >= 2 * INTER * RW) return;
  int rowp = i4 / RW;
  int col4 = i4 - rowp * RW;
  int c = ((rowp >> 5) << 4) + (rowp & 15);
  int u = (rowp >> 4) & 1;
  int srow = u * INTER + c;
  int4 v = reinterpret_cast<const int4*>(in)[(size_t)srow * RW + col4];
  ushort4 o;
  o.x = f2bf((float)v.x); o.y = f2bf((float)v.y);
  o.z = f2bf((float)v.z); o.w = f2bf((float)v.w);
  reinterpret_cast<ushort4*>(out)[i4] = o;
}

// ------- GEMM1: 128x256 tile, 256 threads, 2 INDEPENDENT blocks/CU -------
// Round-16 mechanism: R10's 54% plateau is pipe SERIALIZATION — per 64-K
// tile per CU: MFMA 2483cy + LDS-read 2300cy ~= measured wall 4720cy.
// All 8 waves in one block re-converge at every barrier, so reads and
// MFMAs alternate en masse. Fix: two DECOUPLED 256-thread blocks per CU
// (48KB LDS, ~220 VGPR -> 2 waves/SIMD): block A's barrier/drain stalls
// overlap block B's MFMA (m97/m114 cross-block mechanism).
// Per-CU totals (reads, MFMA, HBM bytes) are arithmetic-identical to R10.
//
// 4 waves (1M x 4N); per-wave 128x64 out = acc[8][4] (same as R10; wr==0).
// BK=32; LDS: A[2][128x32]=16KB + B[2][256x32]=32KB = 48KB.
// Full-drain ledger (trivially race-free): tile t stages t+1 into parity
// pr^1 at tile START (6 loads), computes tile t (~1200cy), then vmcnt(0)
// (loads issued ~1200cy earlier -> cheap) + barrier (WAR for pr reads
// before t+1 re-stages pr... next re-stage of pr is tile t+1 staging t+2,
// after this barrier). Tail: stage no-ops, vmcnt(0) no-op.
// Swizzle: validated R6 family (0 conflicts), same 32-col buffer shape.
// NO t-loop unroll pragma (R11: scratch spill).

__global__ __launch_bounds__(256, 2) void gemm1_2blk(
    const unsigned short* __restrict__ A,   // [NTOK][HIDDEN] bf16
    const unsigned short* __restrict__ B,   // [2I][HIDDEN] bf16 (interleaved)
    const float* __restrict__ scale,        // [2*INTER]
    unsigned short* __restrict__ H)         // [NTOK][INTER] bf16
{
  constexpr int K = HIDDEN;
  constexpr int N = 2 * INTER;
  constexpr int NT = K / 32;                // 96
  __shared__ __align__(16) unsigned short ldsA[2][128 * 32];  // 16 KB
  __shared__ __align__(16) unsigned short ldsB[2][256 * 32];  // 32 KB

  const int nbn = N / 256;                  // 64
  const int nwg = (NTOK / 128) * nbn;       // 4096 (%8==0)
  int bid = blockIdx.x;
  int wg = (bid & 7) * (nwg >> 3) + (bid >> 3);   // XCD-aware bijective swizzle
  const int bm = (wg / nbn) * 128;
  const int bn = (wg % nbn) * 256;

  const int tid  = threadIdx.x;
  const int lane = tid & 63;
  const int wc   = tid >> 6;                // wave id = n-column 0..3

  const int srow = tid >> 2;                // staging rows 0..63 (per inst)
  const int scb  = tid & 3;

  const unsigned short* Ab = A + (size_t)bm * K;
  const unsigned short* Bb = B + (size_t)bn * K;

  auto stageA = [&](int tt) {               // 128 rows = 2 insts
    if (tt >= NT) return;
    int p = tt & 1;
    int kc = tt * 32;
#pragma unroll
    for (int inst = 0; inst < 2; ++inst) {
      int row = inst * 64 + srow;
      gload_lds16(Ab + (size_t)row * K + kc + ((scb ^ ((row >> 1) & 3)) * 8),
                  &ldsA[p][(size_t)(inst * 256 + tid) * 8]);
    }
  };
  auto stageB = [&](int tt) {               // 256 rows = 4 insts
    if (tt >= NT) return;
    int p = tt & 1;
    int kc = tt * 32;
#pragma unroll
    for (int inst = 0; inst < 4; ++inst) {
      int row = inst * 64 + srow;
      gload_lds16(Bb + (size_t)row * K + kc + ((scb ^ ((row >> 1) & 3)) * 8),
                  &ldsB[p][(size_t)(inst * 256 + tid) * 8]);
    }
  };

  auto readA = [&](int p, int m) -> bf16x8 {
    int row = m * 16 + (lane & 15);
    int cb = (lane >> 4) ^ ((row >> 1) & 3);
    return *(const bf16x8*)&ldsA[p][row * 32 + cb * 8];
  };
  auto readB = [&](int p, int n) -> bf16x8 {
    int row = wc * 64 + n * 16 + (lane & 15);
    int cb = (lane >> 4) ^ ((row >> 1) & 3);
    return *(const bf16x8*)&ldsB[p][row * 32 + cb * 8];
  };

  f32x4 acc[8][4] = {};
  bf16x8 aF[8], bF[4];

  // prologue: stage tile 0; drain; converge
  stageA(0);
  stageB(0);
  asm volatile("s_waitcnt vmcnt(0)" ::: "memory");
  __builtin_amdgcn_s_barrier();

  for (int t = 0; t < NT; ++t) {
    const int pr = t & 1;

    // issue next tile's stages first (max time in flight under compute)
    stageA(t + 1);
    stageB(t + 1);

    // read this tile's fragments
#pragma unroll
    for (int m = 0; m < 8; ++m) aF[m] = readA(pr, m);
#pragma unroll
    for (int n = 0; n < 4; ++n) bF[n] = readB(pr, n);

    __builtin_amdgcn_s_setprio(1);
#pragma unroll
    for (int m = 0; m < 8; ++m)
#pragma unroll
      for (int n = 0; n < 4; ++n)
        acc[m][n] = __builtin_amdgcn_mfma_f32_16x16x32_bf16(aF[m], bF[n], acc[m][n], 0, 0, 0);
    __builtin_amdgcn_s_setprio(0);

    // drain t+1's stages (issued ~1 tile ago) + WAR fence for parity reuse
    asm volatile("s_waitcnt vmcnt(0)" ::: "memory");
    __builtin_amdgcn_s_barrier();
  }

  // ---- epilogue: SwiGLU; C/D layout col=lane&15, row=(lane>>4)*4+j ----
  const int crow0 = (lane >> 4) * 4;
  const int ccol  = lane & 15;
  const int hbase = (bn >> 1) + wc * 32;
#pragma unroll
  for (int np = 0; np < 2; ++np) {
    int hcol = hbase + np * 16 + ccol;
    float sg = scale[hcol];
    float su = scale[INTER + hcol];
#pragma unroll
    for (int m = 0; m < 8; ++m) {
#pragma unroll
      for (int j = 0; j < 4; ++j) {
        int row = bm + m * 16 + crow0 + j;
        float g = acc[m][2 * np + 0][j] * sg;
        float u = acc[m][2 * np + 1][j] * su;
        float s = g / (1.0f + __expf(-g));       // silu
        H[(size_t)row * INTER + hcol] = f2bf(u * s);
      }
    }
  }
}

// ------- GEMM2: 256x192 tile, grid 512 (VALIDATED R15, unchanged) -------

__global__ __launch_bounds__(512, 2) void gemm2_192(
    const unsigned short* __restrict__ A,   // [NTOK][INTER] (hb)
    const unsigned short* __restrict__ B,   // [HIDDEN][INTER] (wd)
    const float* __restrict__ scale,        // [HIDDEN]
    float* __restrict__ O)                  // [NTOK][HIDDEN]
{
  constexpr int K = INTER;
  constexpr int NT = K / 64;                // 128
  __shared__ __align__(16) unsigned short lds[2][2][2][256 * 32];

  const int nbn = HIDDEN / 192;             // 16
  const int nwg = (NTOK / 256) * nbn;       // 512 (%8==0)
  int bid = blockIdx.x;
  int wg = (bid & 7) * (nwg >> 3) + (bid >> 3);
  const int bm = (wg / nbn) * 256;
  const int bn = (wg % nbn) * 192;

  const int tid  = threadIdx.x;
  const int lane = tid & 63;
  const int wid  = tid >> 6;
  const int wr = wid >> 2;                  // 0..1 -> m-offset wr*128
  const int wc = wid & 3;                   // 0..3 -> n-offset wc*48

  const int srow0 = tid >> 2;               // staging rows 0..127
  const int srow1 = 128 + (tid >> 2);       // staging rows 128..255
  const int scb   = tid & 3;

  const unsigned short* Ab = A + (size_t)bm * K;
  const unsigned short* Bb = B + (size_t)bn * K;   // rows 192..255 = pad (defined ws mem)

  auto stage = [&](const unsigned short* Gb, int op, int tt, int kh) {
    if (tt >= NT) return;
    int p = tt & 1;
    int kc = tt * 64 + kh * 32;
    unsigned short* lbase = &lds[p][op][kh][0];
    gload_lds16(Gb + (size_t)srow0 * K + kc + ((scb ^ ((srow0 >> 1) & 3)) * 8),
                lbase + (size_t)tid * 8);
    gload_lds16(Gb + (size_t)srow1 * K + kc + ((scb ^ ((srow1 >> 1) & 3)) * 8),
                lbase + (size_t)(512 + tid) * 8);
  };

  auto readA = [&](int p, int kh, int m) -> bf16x8 {
    int row = wr * 128 + m * 16 + (lane & 15);
    int cb = (lane >> 4) ^ ((row >> 1) & 3);
    return *(const bf16x8*)&lds[p][0][kh][row * 32 + cb * 8];
  };
  auto readB = [&](int p, int kh, int n) -> bf16x8 {
    int row = wc * 48 + n * 16 + (lane & 15);     // rows 0..191 only
    int cb = (lane >> 4) ^ ((row >> 1) & 3);
    return *(const bf16x8*)&lds[p][1][kh][row * 32 + cb * 8];
  };

  f32x4 acc[8][3] = {};
  bf16x8 aP[4], aQ[4], bP[3], bQ[3];

  stage(Ab, 0, 0, 0);
  stage(Bb, 1, 0, 0);
  stage(Ab, 0, 0, 1);
  stage(Bb, 1, 0, 1);
  asm volatile("s_waitcnt vmcnt(4)" ::: "memory");
  __builtin_amdgcn_s_barrier();
#pragma unroll
  for (int m = 0; m < 4; ++m) aP[m] = readA(0, 0, m);
#pragma unroll
  for (int n = 0; n < 3; ++n) bP[n] = readB(0, 0, n);

  for (int t = 0; t < NT; ++t) {
    const int pr = t & 1;

#pragma unroll
    for (int m = 0; m < 4; ++m) aQ[m] = readA(pr, 0, m + 4);
    stage(Ab, 0, t + 1, 0);
    __builtin_amdgcn_s_setprio(1);
#pragma unroll
    for (int m = 0; m < 4; ++m)
#pragma unroll
      for (int n = 0; n < 3; ++n)
        acc[m][n] = __builtin_amdgcn_mfma_f32_16x16x32_bf16(aP[m], bP[n], acc[m][n], 0, 0, 0);
    __builtin_amdgcn_s_setprio(0);

    if (t + 1 < NT) {
      asm volatile("s_waitcnt vmcnt(2)" ::: "memory");
    } else {
      asm volatile("s_waitcnt vmcnt(0)" ::: "memory");
    }
    __builtin_amdgcn_s_barrier();
#pragma unroll
    for (int m = 0; m < 4; ++m) aP[m] = readA(pr, 1, m);
#pragma unroll
    for (int n = 0; n < 3; ++n) bQ[n] = readB(pr, 1, n);
    stage(Bb, 1, t + 1, 0);
    __builtin_amdgcn_s_setprio(1);
#pragma unroll
    for (int m = 0; m < 4; ++m)
#pragma unroll
      for (int n = 0; n < 3; ++n)
        acc[m + 4][n] = __builtin_amdgcn_mfma_f32_16x16x32_bf16(aQ[m], bP[n], acc[m + 4][n], 0, 0, 0);
    __builtin_amdgcn_s_setprio(0);

#pragma unroll
    for (int m = 0; m < 4; ++m) aQ[m] = readA(pr, 1, m + 4);
    stage(Ab, 0, t + 1, 1);
    __builtin_amdgcn_s_setprio(1);
#pragma unroll
    for (int m = 0; m < 4; ++m)
#pragma unroll
      for (int n = 0; n < 3; ++n)
        acc[m][n] = __builtin_amdgcn_mfma_f32_16x16x32_bf16(aP[m], bQ[n], acc[m][n], 0, 0, 0);
    __builtin_amdgcn_s_setprio(0);

    asm volatile("s_waitcnt vmcnt(2)" ::: "memory");
    __builtin_amdgcn_s_barrier();
    if (t + 1 < NT) {
#pragma unroll
      for (int m = 0; m < 4; ++m) aP[m] = readA(pr ^ 1, 0, m);
#pragma unroll
      for (int n = 0; n < 3; ++n) bP[n] = readB(pr ^ 1, 0, n);
    }
    stage(Bb, 1, t + 1, 1);
    __builtin_amdgcn_s_setprio(1);
#pragma unroll
    for (int m = 0; m < 4; ++m)
#pragma unroll
      for (int n = 0; n < 3; ++n)
        acc[m + 4][n] = __builtin_amdgcn_mfma_f32_16x16x32_bf16(aQ[m], bQ[n], acc[m + 4][n], 0, 0, 0);
    __builtin_amdgcn_s_setprio(0);
  }

  const int crow0 = (lane >> 4) * 4;
  const int ccol  = lane & 15;
#pragma unroll
  for (int n = 0; n < 3; ++n) {
    int col = bn + wc * 48 + n * 16 + ccol;
    float sc = scale[col];
#pragma unroll
    for (int m = 0; m < 8; ++m) {
#pragma unroll
      for (int j = 0; j < 4; ++j) {
        int row = bm + wr * 128 + m * 16 + crow0 + j;
        O[(size_t)row * HIDDEN + col] = acc[m][n][j] * sc;
      }
    }
  }
}

// ---------------- launch ----------------

extern "C" void kernel_launch(void* const* d_in, const int* in_sizes, int n_in,
                              void* d_out, int out_size, void* d_ws, size_t ws_size,
                              hipStream_t stream) {
  (void)in_sizes; (void)n_in; (void)out_size; (void)ws_size;

  const float* hidden = (const float*)d_in[0];   // [NTOK][HIDDEN] f32
  const int*   guq    = (const int*)d_in[1];     // [2*INTER][HIDDEN] i32
  const float* gus    = (const float*)d_in[2];   // [2*INTER]
  const int*   dwq    = (const int*)d_in[3];     // [HIDDEN][INTER] i32
  const float* dsc    = (const float*)d_in[4];   // [HIDDEN]
  float* out = (float*)d_out;

  char* ws = (char*)d_ws;
  unsigned short* xb  = (unsigned short*)(ws);                      // 50,331,648 B
  unsigned short* wgu = (unsigned short*)(ws + 50331648ull);        // 100,663,296 B (permuted)
  unsigned short* wd  = (unsigned short*)(ws + 150994944ull);       // 50,331,648 B
  unsigned short* hb  = (unsigned short*)(ws + 201326592ull);       // 134,217,728 B
  // total ws use: 335,544,320 B

  {
    int n4 = NTOK * HIDDEN / 4;
    cvt_f32_bf16<<<(n4 + 255) / 256, 256, 0, stream>>>(hidden, xb, n4);
  }
  {
    int n4 = 2 * INTER * HIDDEN / 4;
    cvt_wgu_perm<<<(n4 + 255) / 256, 256, 0, stream>>>(guq, wgu);
  }
  {
    int n4 = HIDDEN * INTER / 4;
    cvt_i32_bf16<<<(n4 + 255) / 256, 256, 0, stream>>>(dwq, wd, n4);
  }

  // GEMM1+SwiGLU: 128x256 tiles, 2 independent blocks/CU, grid 4096
  gemm1_2blk<<<(NTOK / 128) * (2 * INTER / 256), 256, 0, stream>>>(xb, wgu, gus, hb);
  // GEMM2: [8192 x 3072] over K=8192, 256x192 tiles, grid 512 = 2 exact rounds
  gemm2_192<<<(NTOK / 256) * (HIDDEN / 192), 512, 0, stream>>>(hb, wd, dsc, out);
}

// Round 17
// 1329.720 us; speedup vs baseline: 1.1429x; 1.1429x over previous
//
#include <hip/hip_runtime.h>
#include <hip/hip_bf16.h>

#define HIDDEN 3072
#define INTER  8192
#define NTOK   8192   // B*S = 4*2048

typedef __attribute__((ext_vector_type(8))) short bf16x8;
typedef __attribute__((ext_vector_type(4))) float f32x4;

__device__ __forceinline__ void gload_lds16(const void* g, void* l) {
  __builtin_amdgcn_global_load_lds(
      (const __attribute__((address_space(1))) void*)g,
      (__attribute__((address_space(3))) void*)l, 16, 0, 0);
}

__device__ __forceinline__ unsigned short f2bf(float f) {
  unsigned int u = __builtin_bit_cast(unsigned int, f);
  u += 0x7fffu + ((u >> 16) & 1u);   // round-to-nearest-even
  return (unsigned short)(u >> 16);
}

// ---------------- conversion kernels ----------------

__global__ void cvt_f32_bf16(const float* __restrict__ in,
                             unsigned short* __restrict__ out, int n4) {
  int i = blockIdx.x * blockDim.x + threadIdx.x;
  if (i >= n4) return;
  float4 v = reinterpret_cast<const float4*>(in)[i];
  ushort4 o;
  o.x = f2bf(v.x); o.y = f2bf(v.y); o.z = f2bf(v.z); o.w = f2bf(v.w);
  reinterpret_cast<ushort4*>(out)[i] = o;
}

__global__ void cvt_i32_bf16(const int* __restrict__ in,
                             unsigned short* __restrict__ out, int n4) {
  int i = blockIdx.x * blockDim.x + threadIdx.x;
  if (i >= n4) return;
  int4 v = reinterpret_cast<const int4*>(in)[i];
  ushort4 o;
  o.x = f2bf((float)v.x); o.y = f2bf((float)v.y);
  o.z = f2bf((float)v.z); o.w = f2bf((float)v.w);
  reinterpret_cast<ushort4*>(out)[i] = o;
}

// W_gu convert with gate/up row interleave at 16-row granularity:
// W'-row rowp = 32*(c>>4) + 16*u + (c&15), u=0 gate / 1 up.
__global__ void cvt_wgu_perm(const int* __restrict__ in,
                             unsigned short* __restrict__ out) {
  int i4 = blockIdx.x * blockDim.x + threadIdx.x;
  const int RW = HIDDEN / 4;   // 768 int4-groups per row
  if (i4 >= 2 * INTER * RW) return;
  int rowp = i4 / RW;
  int col4 = i4 - rowp * RW;
  int c = ((rowp >> 5) << 4) + (rowp & 15);
  int u = (rowp >> 4) & 1;
  int srow = u * INTER + c;
  int4 v = reinterpret_cast<const int4*>(in)[(size_t)srow * RW + col4];
  ushort4 o;
  o.x = f2bf((float)v.x); o.y = f2bf((float)v.y);
  o.z = f2bf((float)v.z); o.w = f2bf((float)v.w);
  reinterpret_cast<ushort4*>(out)[i4] = o;
}

// ------- 256x256 GEMM, 16x16x32 MFMA, single-sync-per-tile -------
// Round-17: R10's validated ping-pong phases/registers/swizzle, with the
// sync structure reduced from 2 mid-tile (vmcnt+barrier) pairs to ONE
// end-of-tile pair. Mechanism: tile t+1 is staged ENTIRELY at tile-t
// start (8 loads into parity pr^1); the drain vmcnt(0) comes ~4500cy
// later at tile end (loads long landed -> cheap). Tile t's 24 ds_reads
// and 64 MFMAs then form one barrier-free region: reads slide under MFMA
// across all 4 phases (R10's mid-tile barriers only allowed 1-phase
// overlap; measured serial: reads 2300cy + MFMA 2483cy = wall 4720cy).
//
// Ledger: only t+1's 8 stage-loads are ever outstanding; vmcnt(0) at t's
// end drains them; barrier then publishes LDS. Tail t=NT-1: stage no-ops,
// vmcnt(0) no-op, preload skipped.
// RAW: tile t reads parity pr staged at t-1's start, drained at t-1's end
//   barrier. Preload of (t+1) k0 reads pr^1 AFTER the end barrier. ✓
// WAR: stages at t write pr^1; last reads of pr^1 were tile t-1's phase
//   reads + its preload -- all complete before t-1's end barrier (MFMA
//   register deps force the reads; preload precedes next-tile stages in
//   program order and ds ops aren't hoisted past the "memory" asm). ✓
// Swizzle: validated R6 family (0 conflicts). NO t-loop unroll pragma
// (R11: scratch spill). Register structure byte-identical to R10.

template<int K, int N, int MODE>
__global__ __launch_bounds__(512, 2) void gemm8p(
    const unsigned short* __restrict__ A,   // [NTOK][K]
    const unsigned short* __restrict__ B,   // [N][K]
    const float* __restrict__ scale,
    void* __restrict__ outv)
{
  constexpr int NT = K / 64;
  __shared__ __align__(16) unsigned short lds[2][2][2][256 * 32];

  const int nbn = N / 256;
  const int nwg = (NTOK / 256) * nbn;
  int bid = blockIdx.x;
  int wg = (bid & 7) * (nwg >> 3) + (bid >> 3);   // XCD-aware bijective swizzle
  const int bm = (wg / nbn) * 256;
  const int bn = (wg % nbn) * 256;

  const int tid  = threadIdx.x;
  const int lane = tid & 63;
  const int wid  = tid >> 6;
  const int wr = wid >> 2;                  // 0..1
  const int wc = wid & 3;                   // 0..3

  const int srow0 = tid >> 2;               // staging rows 0..127
  const int srow1 = 128 + (tid >> 2);       // staging rows 128..255
  const int scb   = tid & 3;

  const unsigned short* Ab = A + (size_t)bm * K;
  const unsigned short* Bb = B + (size_t)bn * K;

  auto stage = [&](const unsigned short* Gb, int op, int tt, int kh) {
    if (tt >= NT) return;
    int p = tt & 1;
    int kc = tt * 64 + kh * 32;
    unsigned short* lbase = &lds[p][op][kh][0];
    gload_lds16(Gb + (size_t)srow0 * K + kc + ((scb ^ ((srow0 >> 1) & 3)) * 8),
                lbase + (size_t)tid * 8);
    gload_lds16(Gb + (size_t)srow1 * K + kc + ((scb ^ ((srow1 >> 1) & 3)) * 8),
                lbase + (size_t)(512 + tid) * 8);
  };

  auto readA = [&](int p, int kh, int m) -> bf16x8 {
    int row = wr * 128 + m * 16 + (lane & 15);
    int cb = (lane >> 4) ^ ((row >> 1) & 3);
    return *(const bf16x8*)&lds[p][0][kh][row * 32 + cb * 8];
  };
  auto readB = [&](int p, int kh, int n) -> bf16x8 {
    int row = wc * 64 + n * 16 + (lane & 15);
    int cb = (lane >> 4) ^ ((row >> 1) & 3);
    return *(const bf16x8*)&lds[p][1][kh][row * 32 + cb * 8];
  };

  f32x4 acc[8][4] = {};
  bf16x8 aP[4], aQ[4], bP[4], bQ[4];

  // prologue: stage tile 0 fully; drain; converge; preload k0 frags
  stage(Ab, 0, 0, 0);
  stage(Bb, 1, 0, 0);
  stage(Ab, 0, 0, 1);
  stage(Bb, 1, 0, 1);
  asm volatile("s_waitcnt vmcnt(0)" ::: "memory");
  __builtin_amdgcn_s_barrier();
#pragma unroll
  for (int m = 0; m < 4; ++m) aP[m] = readA(0, 0, m);
#pragma unroll
  for (int n = 0; n < 4; ++n) bP[n] = readB(0, 0, n);

  for (int t = 0; t < NT; ++t) {
    const int pr = t & 1;

    // stage ALL of tile t+1 into parity pr^1 (drained at tile end)
    stage(Ab, 0, t + 1, 0);
    stage(Bb, 1, t + 1, 0);
    stage(Ab, 0, t + 1, 1);
    stage(Bb, 1, t + 1, 1);

    // ---- Ph0: MFMA k0/h0 (aP x bP); read A(t,k0,h1)->aQ ----
#pragma unroll
    for (int m = 0; m < 4; ++m) aQ[m] = readA(pr, 0, m + 4);
    __builtin_amdgcn_s_setprio(1);
#pragma unroll
    for (int m = 0; m < 4; ++m)
#pragma unroll
      for (int n = 0; n < 4; ++n)
        acc[m][n] = __builtin_amdgcn_mfma_f32_16x16x32_bf16(aP[m], bP[n], acc[m][n], 0, 0, 0);
    __builtin_amdgcn_s_setprio(0);

    // ---- Ph1: read A(t,k1,h0)->aP, B(t,k1)->bQ; MFMA k0/h1 (aQ x bP) ----
#pragma unroll
    for (int m = 0; m < 4; ++m) aP[m] = readA(pr, 1, m);
#pragma unroll
    for (int n = 0; n < 4; ++n) bQ[n] = readB(pr, 1, n);
    __builtin_amdgcn_s_setprio(1);
#pragma unroll
    for (int m = 0; m < 4; ++m)
#pragma unroll
      for (int n = 0; n < 4; ++n)
        acc[m + 4][n] = __builtin_amdgcn_mfma_f32_16x16x32_bf16(aQ[m], bP[n], acc[m + 4][n], 0, 0, 0);
    __builtin_amdgcn_s_setprio(0);

    // ---- Ph2: read A(t,k1,h1)->aQ; MFMA k1/h0 (aP x bQ) ----
#pragma unroll
    for (int m = 0; m < 4; ++m) aQ[m] = readA(pr, 1, m + 4);
    __builtin_amdgcn_s_setprio(1);
#pragma unroll
    for (int m = 0; m < 4; ++m)
#pragma unroll
      for (int n = 0; n < 4; ++n)
        acc[m][n] = __builtin_amdgcn_mfma_f32_16x16x32_bf16(aP[m], bQ[n], acc[m][n], 0, 0, 0);
    __builtin_amdgcn_s_setprio(0);

    // ---- Ph3: MFMA k1/h1 (aQ x bQ) ----
    __builtin_amdgcn_s_setprio(1);
#pragma unroll
    for (int m = 0; m < 4; ++m)
#pragma unroll
      for (int n = 0; n < 4; ++n)
        acc[m + 4][n] = __builtin_amdgcn_mfma_f32_16x16x32_bf16(aQ[m], bQ[n], acc[m + 4][n], 0, 0, 0);
    __builtin_amdgcn_s_setprio(0);

    // ---- single end-of-tile sync: drain t+1's stages; publish; preload ----
    asm volatile("s_waitcnt vmcnt(0)" ::: "memory");
    __builtin_amdgcn_s_barrier();
    if (t + 1 < NT) {
#pragma unroll
      for (int m = 0; m < 4; ++m) aP[m] = readA(pr ^ 1, 0, m);
#pragma unroll
      for (int n = 0; n < 4; ++n) bP[n] = readB(pr ^ 1, 0, n);
    }
  }

  // ---- epilogue: C/D layout col=lane&15, row=(lane>>4)*4+j ----
  const int crow0 = (lane >> 4) * 4;
  const int ccol  = lane & 15;
  if constexpr (MODE == 1) {
    // SwiGLU: n-frags (gate,up,gate,up) via 16-granular W interleave
    unsigned short* H = (unsigned short*)outv;     // [NTOK][INTER]
    const int hbase = (bn >> 1) + wc * 32;
#pragma unroll
    for (int np = 0; np < 2; ++np) {
      int hcol = hbase + np * 16 + ccol;
      float sg = scale[hcol];
      float su = scale[INTER + hcol];
#pragma unroll
      for (int m = 0; m < 8; ++m) {
#pragma unroll
        for (int j = 0; j < 4; ++j) {
          int row = bm + wr * 128 + m * 16 + crow0 + j;
          float g = acc[m][2 * np + 0][j] * sg;
          float u = acc[m][2 * np + 1][j] * su;
          float s = g / (1.0f + __expf(-g));       // silu
          H[(size_t)row * INTER + hcol] = f2bf(u * s);
        }
      }
    }
  } else {
    float* O = (float*)outv;                       // [NTOK][N]
#pragma unroll
    for (int n = 0; n < 4; ++n) {
      int col = bn + wc * 64 + n * 16 + ccol;
      float sc = scale[col];
#pragma unroll
      for (int m = 0; m < 8; ++m) {
#pragma unroll
        for (int j = 0; j < 4; ++j) {
          int row = bm + wr * 128 + m * 16 + crow0 + j;
          O[(size_t)row * N + col] = acc[m][n][j] * sc;
        }
      }
    }
  }
}

// ---------------- launch ----------------

extern "C" void kernel_launch(void* const* d_in, const int* in_sizes, int n_in,
                              void* d_out, int out_size, void* d_ws, size_t ws_size,
                              hipStream_t stream) {
  (void)in_sizes; (void)n_in; (void)out_size; (void)ws_size;

  const float* hidden = (const float*)d_in[0];   // [NTOK][HIDDEN] f32
  const int*   guq    = (const int*)d_in[1];     // [2*INTER][HIDDEN] i32
  const float* gus    = (const float*)d_in[2];   // [2*INTER]
  const int*   dwq    = (const int*)d_in[3];     // [HIDDEN][INTER] i32
  const float* dsc    = (const float*)d_in[4];   // [HIDDEN]
  float* out = (float*)d_out;

  char* ws = (char*)d_ws;
  unsigned short* xb  = (unsigned short*)(ws);                      // 50,331,648 B
  unsigned short* wgu = (unsigned short*)(ws + 50331648ull);        // 100,663,296 B (permuted)
  unsigned short* wd  = (unsigned short*)(ws + 150994944ull);       // 50,331,648 B
  unsigned short* hb  = (unsigned short*)(ws + 201326592ull);       // 134,217,728 B
  // total ws use: 335,544,320 B

  {
    int n4 = NTOK * HIDDEN / 4;
    cvt_f32_bf16<<<(n4 + 255) / 256, 256, 0, stream>>>(hidden, xb, n4);
  }
  {
    int n4 = 2 * INTER * HIDDEN / 4;
    cvt_wgu_perm<<<(n4 + 255) / 256, 256, 0, stream>>>(guq, wgu);
  }
  {
    int n4 = HIDDEN * INTER / 4;
    cvt_i32_bf16<<<(n4 + 255) / 256, 256, 0, stream>>>(dwq, wd, n4);
  }

  // GEMM1+SwiGLU: [8192 x 16384] over K=3072, writes H bf16 [8192][8192]
  gemm8p<HIDDEN, 2 * INTER, 1>
      <<<(NTOK / 256) * (2 * INTER / 256), 512, 0, stream>>>(xb, wgu, gus, hb);
  // GEMM2: [8192 x 3072] over K=8192, 256x256 tiles, f32 store
  gemm8p<INTER, HIDDEN, 2>
      <<<(NTOK / 256) * (HIDDEN / 256), 512, 0, stream>>>(hb, wd, dsc, out);
}

// Round 18
// 1246.355 us; speedup vs baseline: 1.2193x; 1.0669x over previous
//
#include <hip/hip_runtime.h>
#include <hip/hip_bf16.h>

#define HIDDEN 3072
#define INTER  8192
#define NTOK   8192   // B*S = 4*2048

typedef __attribute__((ext_vector_type(8))) short bf16x8;
typedef __attribute__((ext_vector_type(4))) float f32x4;

__device__ __forceinline__ void gload_lds16(const void* g, void* l) {
  __builtin_amdgcn_global_load_lds(
      (const __attribute__((address_space(1))) void*)g,
      (__attribute__((address_space(3))) void*)l, 16, 0, 0);
}

__device__ __forceinline__ unsigned short f2bf(float f) {
  unsigned int u = __builtin_bit_cast(unsigned int, f);
  u += 0x7fffu + ((u >> 16) & 1u);   // round-to-nearest-even
  return (unsigned short)(u >> 16);
}

// ---------------- conversion kernels ----------------

__global__ void cvt_f32_bf16(const float* __restrict__ in,
                             unsigned short* __restrict__ out, int n4) {
  int i = blockIdx.x * blockDim.x + threadIdx.x;
  if (i >= n4) return;
  float4 v = reinterpret_cast<const float4*>(in)[i];
  ushort4 o;
  o.x = f2bf(v.x); o.y = f2bf(v.y); o.z = f2bf(v.z); o.w = f2bf(v.w);
  reinterpret_cast<ushort4*>(out)[i] = o;
}

__global__ void cvt_i32_bf16(const int* __restrict__ in,
                             unsigned short* __restrict__ out, int n4) {
  int i = blockIdx.x * blockDim.x + threadIdx.x;
  if (i >= n4) return;
  int4 v = reinterpret_cast<const int4*>(in)[i];
  ushort4 o;
  o.x = f2bf((float)v.x); o.y = f2bf((float)v.y);
  o.z = f2bf((float)v.z); o.w = f2bf((float)v.w);
  reinterpret_cast<ushort4*>(out)[i] = o;
}

// W_gu convert with gate/up row interleave at 16-row granularity:
// W'-row rowp = 32*(c>>4) + 16*u + (c&15), u=0 gate / 1 up.
__global__ void cvt_wgu_perm(const int* __restrict__ in,
                             unsigned short* __restrict__ out) {
  int i4 = blockIdx.x * blockDim.x + threadIdx.x;
  const int RW = HIDDEN / 4;   // 768 int4-groups per row
  if (i4 >= 2 * INTER * RW) return;
  int rowp = i4 / RW;
  int col4 = i4 - rowp * RW;
  int c = ((rowp >> 5) << 4) + (rowp & 15);
  int u = (rowp >> 4) & 1;
  int srow = u * INTER + c;
  int4 v = reinterpret_cast<const int4*>(in)[(size_t)srow * RW + col4];
  ushort4 o;
  o.x = f2bf((float)v.x); o.y = f2bf((float)v.y);
  o.z = f2bf((float)v.z); o.w = f2bf((float)v.w);
  reinterpret_cast<ushort4*>(out)[i4] = o;
}

// ------- GEMM1: 256x256, 16x16x32 MFMA, phase-pipelined fragments -------
// BYTE-EXACT R10 structure — the measured local optimum of the schedule
// family after 9 bracketing experiments (lockstep 48.5 / drift 52.6 /
// ping-pong 54.5 / hoist 54.0 / lockstep+lgkm 48.6 / 2blk 34 / 1sync 46.5).
// NO t-loop unroll pragma (R11: scratch spill, 2.7x). See R10 for ledger.

template<int K, int N, int MODE>
__global__ __launch_bounds__(512, 2) void gemm8p(
    const unsigned short* __restrict__ A,   // [NTOK][K]
    const unsigned short* __restrict__ B,   // [N][K]
    const float* __restrict__ scale,
    void* __restrict__ outv)
{
  constexpr int NT = K / 64;
  __shared__ __align__(16) unsigned short lds[2][2][2][256 * 32];

  const int nbn = N / 256;
  const int nwg = (NTOK / 256) * nbn;
  int bid = blockIdx.x;
  int wg = (bid & 7) * (nwg >> 3) + (bid >> 3);   // XCD-aware bijective swizzle
  const int bm = (wg / nbn) * 256;
  const int bn = (wg % nbn) * 256;

  const int tid  = threadIdx.x;
  const int lane = tid & 63;
  const int wid  = tid >> 6;
  const int wr = wid >> 2;                  // 0..1
  const int wc = wid & 3;                   // 0..3

  const int srow0 = tid >> 2;               // staging rows 0..127
  const int srow1 = 128 + (tid >> 2);       // staging rows 128..255
  const int scb   = tid & 3;

  const unsigned short* Ab = A + (size_t)bm * K;
  const unsigned short* Bb = B + (size_t)bn * K;

  auto stage = [&](const unsigned short* Gb, int op, int tt, int kh) {
    if (tt >= NT) return;
    int p = tt & 1;
    int kc = tt * 64 + kh * 32;
    unsigned short* lbase = &lds[p][op][kh][0];
    gload_lds16(Gb + (size_t)srow0 * K + kc + ((scb ^ ((srow0 >> 1) & 3)) * 8),
                lbase + (size_t)tid * 8);
    gload_lds16(Gb + (size_t)srow1 * K + kc + ((scb ^ ((srow1 >> 1) & 3)) * 8),
                lbase + (size_t)(512 + tid) * 8);
  };

  auto readA = [&](int p, int kh, int m) -> bf16x8 {
    int row = wr * 128 + m * 16 + (lane & 15);
    int cb = (lane >> 4) ^ ((row >> 1) & 3);
    return *(const bf16x8*)&lds[p][0][kh][row * 32 + cb * 8];
  };
  auto readB = [&](int p, int kh, int n) -> bf16x8 {
    int row = wc * 64 + n * 16 + (lane & 15);
    int cb = (lane >> 4) ^ ((row >> 1) & 3);
    return *(const bf16x8*)&lds[p][1][kh][row * 32 + cb * 8];
  };

  f32x4 acc[8][4] = {};
  bf16x8 aP[4], aQ[4], bP[4], bQ[4];

  // prologue: stage tile 0 (4 half-tiles); drain k0; preload aP/bP
  stage(Ab, 0, 0, 0);
  stage(Bb, 1, 0, 0);
  stage(Ab, 0, 0, 1);
  stage(Bb, 1, 0, 1);
  asm volatile("s_waitcnt vmcnt(4)" ::: "memory");
  __builtin_amdgcn_s_barrier();
#pragma unroll
  for (int m = 0; m < 4; ++m) aP[m] = readA(0, 0, m);
#pragma unroll
  for (int n = 0; n < 4; ++n) bP[n] = readB(0, 0, n);

  for (int t = 0; t < NT; ++t) {
    const int pr = t & 1;

    // ---- Ph0: MFMA k0/h0 (aP x bP); read A(t,k0,h1)->aQ ----
#pragma unroll
    for (int m = 0; m < 4; ++m) aQ[m] = readA(pr, 0, m + 4);
    stage(Ab, 0, t + 1, 0);
    __builtin_amdgcn_s_setprio(1);
#pragma unroll
    for (int m = 0; m < 4; ++m)
#pragma unroll
      for (int n = 0; n < 4; ++n)
        acc[m][n] = __builtin_amdgcn_mfma_f32_16x16x32_bf16(aP[m], bP[n], acc[m][n], 0, 0, 0);
    __builtin_amdgcn_s_setprio(0);

    // ---- Ph1: drain kh1(t); BAR; read A(t,k1,h0)->aP, B(t,k1)->bQ;
    //           MFMA k0/h1 (aQ x bP) ----
    if (t + 1 < NT) {
      asm volatile("s_waitcnt vmcnt(2)" ::: "memory");
    } else {
      asm volatile("s_waitcnt vmcnt(0)" ::: "memory");
    }
    __builtin_amdgcn_s_barrier();
#pragma unroll
    for (int m = 0; m < 4; ++m) aP[m] = readA(pr, 1, m);
#pragma unroll
    for (int n = 0; n < 4; ++n) bQ[n] = readB(pr, 1, n);
    stage(Bb, 1, t + 1, 0);
    __builtin_amdgcn_s_setprio(1);
#pragma unroll
    for (int m = 0; m < 4; ++m)
#pragma unroll
      for (int n = 0; n < 4; ++n)
        acc[m + 4][n] = __builtin_amdgcn_mfma_f32_16x16x32_bf16(aQ[m], bP[n], acc[m + 4][n], 0, 0, 0);
    __builtin_amdgcn_s_setprio(0);

    // ---- Ph2: read A(t,k1,h1)->aQ; MFMA k1/h0 (aP x bQ); no barrier ----
#pragma unroll
    for (int m = 0; m < 4; ++m) aQ[m] = readA(pr, 1, m + 4);
    stage(Ab, 0, t + 1, 1);
    __builtin_amdgcn_s_setprio(1);
#pragma unroll
    for (int m = 0; m < 4; ++m)
#pragma unroll
      for (int n = 0; n < 4; ++n)
        acc[m][n] = __builtin_amdgcn_mfma_f32_16x16x32_bf16(aP[m], bQ[n], acc[m][n], 0, 0, 0);
    __builtin_amdgcn_s_setprio(0);

    // ---- Ph3: drain k0(t+1); BAR; read A(t+1,k0,h0)->aP, B(t+1,k0)->bP;
    //           MFMA k1/h1 (aQ x bQ) ----
    asm volatile("s_waitcnt vmcnt(2)" ::: "memory");
    __builtin_amdgcn_s_barrier();
    if (t + 1 < NT) {
#pragma unroll
      for (int m = 0; m < 4; ++m) aP[m] = readA(pr ^ 1, 0, m);
#pragma unroll
      for (int n = 0; n < 4; ++n) bP[n] = readB(pr ^ 1, 0, n);
    }
    stage(Bb, 1, t + 1, 1);
    __builtin_amdgcn_s_setprio(1);
#pragma unroll
    for (int m = 0; m < 4; ++m)
#pragma unroll
      for (int n = 0; n < 4; ++n)
        acc[m + 4][n] = __builtin_amdgcn_mfma_f32_16x16x32_bf16(aQ[m], bQ[n], acc[m + 4][n], 0, 0, 0);
    __builtin_amdgcn_s_setprio(0);
  }

  // ---- epilogue: C/D layout col=lane&15, row=(lane>>4)*4+j ----
  const int crow0 = (lane >> 4) * 4;
  const int ccol  = lane & 15;
  if constexpr (MODE == 1) {
    // SwiGLU: n-frags (gate,up,gate,up) via 16-granular W interleave
    unsigned short* H = (unsigned short*)outv;     // [NTOK][INTER]
    const int hbase = (bn >> 1) + wc * 32;
#pragma unroll
    for (int np = 0; np < 2; ++np) {
      int hcol = hbase + np * 16 + ccol;
      float sg = scale[hcol];
      float su = scale[INTER + hcol];
#pragma unroll
      for (int m = 0; m < 8; ++m) {
#pragma unroll
        for (int j = 0; j < 4; ++j) {
          int row = bm + wr * 128 + m * 16 + crow0 + j;
          float g = acc[m][2 * np + 0][j] * sg;
          float u = acc[m][2 * np + 1][j] * su;
          float s = g / (1.0f + __expf(-g));       // silu
          H[(size_t)row * INTER + hcol] = f2bf(u * s);
        }
      }
    }
  } else {
    float* O = (float*)outv;                       // [NTOK][N]
#pragma unroll
    for (int n = 0; n < 4; ++n) {
      int col = bn + wc * 64 + n * 16 + ccol;
      float sc = scale[col];
#pragma unroll
      for (int m = 0; m < 8; ++m) {
#pragma unroll
        for (int j = 0; j < 4; ++j) {
          int row = bm + wr * 128 + m * 16 + crow0 + j;
          O[(size_t)row * N + col] = acc[m][n][j] * sc;
        }
      }
    }
  }
}

// ------- GEMM2: 256x192 tile, grid 512 = EXACTLY 2 full CU-rounds -------
// VALIDATED R15 kernel (equivalent-to-best; balanced grid, plain stores).
// B LDS buffer padded to 256 rows so staging is byte-identical to the
// proven R10 2-loads/stage ledger (pad rows stage garbage from defined ws
// memory, never read). Per wave: 128x48 out = acc[8][3].

__global__ __launch_bounds__(512, 2) void gemm2_192(
    const unsigned short* __restrict__ A,   // [NTOK][INTER] (hb)
    const unsigned short* __restrict__ B,   // [HIDDEN][INTER] (wd)
    const float* __restrict__ scale,        // [HIDDEN]
    float* __restrict__ O)                  // [NTOK][HIDDEN]
{
  constexpr int K = INTER;
  constexpr int NT = K / 64;                // 128
  __shared__ __align__(16) unsigned short lds[2][2][2][256 * 32];

  const int nbn = HIDDEN / 192;             // 16
  const int nwg = (NTOK / 256) * nbn;       // 512 (%8==0)
  int bid = blockIdx.x;
  int wg = (bid & 7) * (nwg >> 3) + (bid >> 3);
  const int bm = (wg / nbn) * 256;
  const int bn = (wg % nbn) * 192;

  const int tid  = threadIdx.x;
  const int lane = tid & 63;
  const int wid  = tid >> 6;
  const int wr = wid >> 2;                  // 0..1 -> m-offset wr*128
  const int wc = wid & 3;                   // 0..3 -> n-offset wc*48

  const int srow0 = tid >> 2;               // staging rows 0..127
  const int srow1 = 128 + (tid >> 2);       // staging rows 128..255
  const int scb   = tid & 3;

  const unsigned short* Ab = A + (size_t)bm * K;
  const unsigned short* Bb = B + (size_t)bn * K;   // rows 192..255 = pad (defined ws mem)

  auto stage = [&](const unsigned short* Gb, int op, int tt, int kh) {
    if (tt >= NT) return;
    int p = tt & 1;
    int kc = tt * 64 + kh * 32;
    unsigned short* lbase = &lds[p][op][kh][0];
    gload_lds16(Gb + (size_t)srow0 * K + kc + ((scb ^ ((srow0 >> 1) & 3)) * 8),
                lbase + (size_t)tid * 8);
    gload_lds16(Gb + (size_t)srow1 * K + kc + ((scb ^ ((srow1 >> 1) & 3)) * 8),
                lbase + (size_t)(512 + tid) * 8);
  };

  auto readA = [&](int p, int kh, int m) -> bf16x8 {
    int row = wr * 128 + m * 16 + (lane & 15);
    int cb = (lane >> 4) ^ ((row >> 1) & 3);
    return *(const bf16x8*)&lds[p][0][kh][row * 32 + cb * 8];
  };
  auto readB = [&](int p, int kh, int n) -> bf16x8 {
    int row = wc * 48 + n * 16 + (lane & 15);     // rows 0..191 only
    int cb = (lane >> 4) ^ ((row >> 1) & 3);
    return *(const bf16x8*)&lds[p][1][kh][row * 32 + cb * 8];
  };

  f32x4 acc[8][3] = {};
  bf16x8 aP[4], aQ[4], bP[3], bQ[3];

  stage(Ab, 0, 0, 0);
  stage(Bb, 1, 0, 0);
  stage(Ab, 0, 0, 1);
  stage(Bb, 1, 0, 1);
  asm volatile("s_waitcnt vmcnt(4)" ::: "memory");
  __builtin_amdgcn_s_barrier();
#pragma unroll
  for (int m = 0; m < 4; ++m) aP[m] = readA(0, 0, m);
#pragma unroll
  for (int n = 0; n < 3; ++n) bP[n] = readB(0, 0, n);

  for (int t = 0; t < NT; ++t) {
    const int pr = t & 1;

#pragma unroll
    for (int m = 0; m < 4; ++m) aQ[m] = readA(pr, 0, m + 4);
    stage(Ab, 0, t + 1, 0);
    __builtin_amdgcn_s_setprio(1);
#pragma unroll
    for (int m = 0; m < 4; ++m)
#pragma unroll
      for (int n = 0; n < 3; ++n)
        acc[m][n] = __builtin_amdgcn_mfma_f32_16x16x32_bf16(aP[m], bP[n], acc[m][n], 0, 0, 0);
    __builtin_amdgcn_s_setprio(0);

    if (t + 1 < NT) {
      asm volatile("s_waitcnt vmcnt(2)" ::: "memory");
    } else {
      asm volatile("s_waitcnt vmcnt(0)" ::: "memory");
    }
    __builtin_amdgcn_s_barrier();
#pragma unroll
    for (int m = 0; m < 4; ++m) aP[m] = readA(pr, 1, m);
#pragma unroll
    for (int n = 0; n < 3; ++n) bQ[n] = readB(pr, 1, n);
    stage(Bb, 1, t + 1, 0);
    __builtin_amdgcn_s_setprio(1);
#pragma unroll
    for (int m = 0; m < 4; ++m)
#pragma unroll
      for (int n = 0; n < 3; ++n)
        acc[m + 4][n] = __builtin_amdgcn_mfma_f32_16x16x32_bf16(aQ[m], bP[n], acc[m + 4][n], 0, 0, 0);
    __builtin_amdgcn_s_setprio(0);

#pragma unroll
    for (int m = 0; m < 4; ++m) aQ[m] = readA(pr, 1, m + 4);
    stage(Ab, 0, t + 1, 1);
    __builtin_amdgcn_s_setprio(1);
#pragma unroll
    for (int m = 0; m < 4; ++m)
#pragma unroll
      for (int n = 0; n < 3; ++n)
        acc[m][n] = __builtin_amdgcn_mfma_f32_16x16x32_bf16(aP[m], bQ[n], acc[m][n], 0, 0, 0);
    __builtin_amdgcn_s_setprio(0);

    asm volatile("s_waitcnt vmcnt(2)" ::: "memory");
    __builtin_amdgcn_s_barrier();
    if (t + 1 < NT) {
#pragma unroll
      for (int m = 0; m < 4; ++m) aP[m] = readA(pr ^ 1, 0, m);
#pragma unroll
      for (int n = 0; n < 3; ++n) bP[n] = readB(pr ^ 1, 0, n);
    }
    stage(Bb, 1, t + 1, 1);
    __builtin_amdgcn_s_setprio(1);
#pragma unroll
    for (int m = 0; m < 4; ++m)
#pragma unroll
      for (int n = 0; n < 3; ++n)
        acc[m + 4][n] = __builtin_amdgcn_mfma_f32_16x16x32_bf16(aQ[m], bQ[n], acc[m + 4][n], 0, 0, 0);
    __builtin_amdgcn_s_setprio(0);
  }

  const int crow0 = (lane >> 4) * 4;
  const int ccol  = lane & 15;
#pragma unroll
  for (int n = 0; n < 3; ++n) {
    int col = bn + wc * 48 + n * 16 + ccol;
    float sc = scale[col];
#pragma unroll
    for (int m = 0; m < 8; ++m) {
#pragma unroll
      for (int j = 0; j < 4; ++j) {
        int row = bm + wr * 128 + m * 16 + crow0 + j;
        O[(size_t)row * HIDDEN + col] = acc[m][n][j] * sc;
      }
    }
  }
}

// ---------------- launch ----------------

extern "C" void kernel_launch(void* const* d_in, const int* in_sizes, int n_in,
                              void* d_out, int out_size, void* d_ws, size_t ws_size,
                              hipStream_t stream) {
  (void)in_sizes; (void)n_in; (void)out_size; (void)ws_size;

  const float* hidden = (const float*)d_in[0];   // [NTOK][HIDDEN] f32
  const int*   guq    = (const int*)d_in[1];     // [2*INTER][HIDDEN] i32
  const float* gus    = (const float*)d_in[2];   // [2*INTER]
  const int*   dwq    = (const int*)d_in[3];     // [HIDDEN][INTER] i32
  const float* dsc    = (const float*)d_in[4];   // [HIDDEN]
  float* out = (float*)d_out;

  char* ws = (char*)d_ws;
  unsigned short* xb  = (unsigned short*)(ws);                      // 50,331,648 B
  unsigned short* wgu = (unsigned short*)(ws + 50331648ull);        // 100,663,296 B (permuted)
  unsigned short* wd  = (unsigned short*)(ws + 150994944ull);       // 50,331,648 B
  unsigned short* hb  = (unsigned short*)(ws + 201326592ull);       // 134,217,728 B
  // total ws use: 335,544,320 B

  {
    int n4 = NTOK * HIDDEN / 4;
    cvt_f32_bf16<<<(n4 + 255) / 256, 256, 0, stream>>>(hidden, xb, n4);
  }
  {
    int n4 = 2 * INTER * HIDDEN / 4;
    cvt_wgu_perm<<<(n4 + 255) / 256, 256, 0, stream>>>(guq, wgu);
  }
  {
    int n4 = HIDDEN * INTER / 4;
    cvt_i32_bf16<<<(n4 + 255) / 256, 256, 0, stream>>>(dwq, wd, n4);
  }

  // GEMM1+SwiGLU: [8192 x 16384] over K=3072, writes H bf16 [8192][8192]
  gemm8p<HIDDEN, 2 * INTER, 1>
      <<<(NTOK / 256) * (2 * INTER / 256), 512, 0, stream>>>(xb, wgu, gus, hb);
  // GEMM2: [8192 x 3072] over K=8192, 256x192 tiles, grid 512 = 2 exact rounds
  gemm2_192<<<(NTOK / 256) * (HIDDEN / 192), 512, 0, stream>>>(hb, wd, dsc, out);
}